// Round 15
// baseline (805.295 us; speedup 1.0000x reference)
//
#include <hip/hip_runtime.h>
#include <hip/hip_bf16.h>

// ---------------------------------------------------------------------------
// RecurrentBattleNet: 2-layer LSTM (B=512, T=256, IN=512, H=128) + FC head.
// Round 15: two-set software-pipelined dual-rec. Each block's 4 rows split
// into sets P(0-1)/Q(2-3) staggered half a step: every barrier interval runs
// MFMA(one set) CONCURRENT with ew(other set) on separate pipes (R14 ran
// them in alternate intervals -> cost was their sum). MFMA C-rows depend
// only on same A-rows, so one 16-row tile holds both sets at different
// times; in-flux rows only corrupt discarded C rows. Consumer folds
// Wi1+Wh1 into same waves (128 AGPR) -> single gate buffer per set; h0
// half-image DMA lands in rows the current MFMA discards. setprio on MFMA.
// ---------------------------------------------------------------------------

#define BATCH 512
#define SEQT  256
#define INPUTD 512
#define HID   128
#define GATES 512   // 4*HID
#define RB    4     // batch rows per recurrence block
#define SUBS  16    // producer->consumer flag granularity (steps)
#define NCH   (SEQT / SUBS)

typedef __bf16 bf16_t;
typedef bf16_t bf16x4 __attribute__((ext_vector_type(4)));
typedef bf16_t bf16x8 __attribute__((ext_vector_type(8)));
typedef float  f32x4  __attribute__((ext_vector_type(4)));

__device__ __forceinline__ float sigm(float x) {
    return __builtin_amdgcn_rcpf(1.f + __expf(-x));
}
__device__ __forceinline__ float tanhfast(float x) {
    float xc = fminf(fmaxf(x, -15.f), 15.f);
    float e = __expf(2.f * xc);
    return (e - 1.f) * __builtin_amdgcn_rcpf(e + 1.f);
}

// ---------------------------------------------------------------------------
// fp32 -> bf16 conversion, vectorized. n4 = n/4.
// ---------------------------------------------------------------------------
__global__ __launch_bounds__(256) void cvt_f32_bf16(
    const float* __restrict__ in, bf16_t* __restrict__ out, long n4)
{
    long i = (long)blockIdx.x * 256 + threadIdx.x;
    long stride = (long)gridDim.x * 256;
    for (; i < n4; i += stride) {
        float4 v = ((const float4*)in)[i];
        bf16x4 r;
        r[0] = (bf16_t)v.x; r[1] = (bf16_t)v.y;
        r[2] = (bf16_t)v.z; r[3] = (bf16_t)v.w;
        ((bf16x4*)out)[i] = r;
    }
}

// all 4 weight matrices in one launch (fewer launch gaps)
__global__ __launch_bounds__(256) void cvt_weights(
    const float* __restrict__ w0, const float* __restrict__ w1,
    const float* __restrict__ w2, const float* __restrict__ w3,
    bf16_t* __restrict__ o0, bf16_t* __restrict__ o1,
    bf16_t* __restrict__ o2, bf16_t* __restrict__ o3)
{
    int b = blockIdx.x;
    const float* src; bf16_t* dst; long base;
    if (b < 256)      { src = w0; dst = o0; base = (long)b * 256; }
    else if (b < 320) { src = w1; dst = o1; base = (long)(b - 256) * 256; }
    else if (b < 384) { src = w2; dst = o2; base = (long)(b - 320) * 256; }
    else              { src = w3; dst = o3; base = (long)(b - 384) * 256; }
    long i = base + threadIdx.x;
    float4 v = ((const float4*)src)[i];
    bf16x4 r;
    r[0] = (bf16_t)v.x; r[1] = (bf16_t)v.y;
    r[2] = (bf16_t)v.z; r[3] = (bf16_t)v.w;
    ((bf16x4*)dst)[i] = r;
}

// ---------------------------------------------------------------------------
// bf16 MFMA GEMM (layer-0 input projection) writing gate-major xp:
//   xp4[b>>2][t][gate][(b&3)*128 + hid]   (float)
// ---------------------------------------------------------------------------
__global__ __launch_bounds__(256) void gemm_mfma(
    const bf16_t* __restrict__ A, const bf16_t* __restrict__ W,
    const float* __restrict__ b1, const float* __restrict__ b2,
    float* __restrict__ out,
    int K, int tcs, int tcmask, int srcT, int t0)
{
    __shared__ bf16_t As[128 * 32];
    __shared__ bf16_t Bs[128 * 32];
    int tid = threadIdx.x;
    int l = tid & 63;
    int w = tid >> 6;
    int wm = w >> 1, wn = w & 1;
    int bn = blockIdx.x;
    int bm = blockIdx.y;
    int Tc = tcmask + 1;

    long aoff[2], boff[2];
    #pragma unroll
    for (int c = 0; c < 2; ++c) {
        int m = bm * 128 + (tid >> 2) + 64 * c;
        int xr = ((m >> tcs) * srcT) + t0 + (m & tcmask);
        aoff[c] = (long)xr * K + (tid & 3) * 8;
        int n = bn * 128 + (tid >> 2) + 64 * c;
        boff[c] = (long)n * K + (tid & 3) * 8;
    }

    f32x4 acc[4][4];
    #pragma unroll
    for (int i = 0; i < 4; ++i)
        #pragma unroll
        for (int j = 0; j < 4; ++j)
            acc[i][j] = (f32x4){0.f, 0.f, 0.f, 0.f};

    const int rbase = wm * 64 + (l & 15);
    const int cbase = wn * 64 + (l & 15);
    const int kfrag = (l >> 4) * 8;

    for (int kt = 0; kt < K; kt += 32) {
        __builtin_amdgcn_global_load_lds(
            (const __attribute__((address_space(1))) void*)(A + aoff[0] + kt),
            (__attribute__((address_space(3))) void*)(As + tid * 8), 16, 0, 0);
        __builtin_amdgcn_global_load_lds(
            (const __attribute__((address_space(1))) void*)(A + aoff[1] + kt),
            (__attribute__((address_space(3))) void*)(As + 2048 + tid * 8), 16, 0, 0);
        __builtin_amdgcn_global_load_lds(
            (const __attribute__((address_space(1))) void*)(W + boff[0] + kt),
            (__attribute__((address_space(3))) void*)(Bs + tid * 8), 16, 0, 0);
        __builtin_amdgcn_global_load_lds(
            (const __attribute__((address_space(1))) void*)(W + boff[1] + kt),
            (__attribute__((address_space(3))) void*)(Bs + 2048 + tid * 8), 16, 0, 0);
        __syncthreads();

        bf16x8 af[4], bfr[4];
        #pragma unroll
        for (int i = 0; i < 4; ++i)
            af[i] = *(const bf16x8*)(As + (rbase + i * 16) * 32 + kfrag);
        #pragma unroll
        for (int j = 0; j < 4; ++j)
            bfr[j] = *(const bf16x8*)(Bs + (cbase + j * 16) * 32 + kfrag);

        #pragma unroll
        for (int i = 0; i < 4; ++i)
            #pragma unroll
            for (int j = 0; j < 4; ++j)
                acc[i][j] = __builtin_amdgcn_mfma_f32_16x16x32_bf16(
                    af[i], bfr[j], acc[i][j], 0, 0, 0);
        __syncthreads();
    }

    #pragma unroll
    for (int i = 0; i < 4; ++i) {
        int m0 = bm * 128 + wm * 64 + i * 16 + (l >> 4) * 4;
        #pragma unroll
        for (int j = 0; j < 4; ++j) {
            int n = bn * 128 + wn * 64 + j * 16 + (l & 15);
            float bb = b1[n] + b2[n];
            int hid = n & 127;          // g == bn
            #pragma unroll
            for (int r = 0; r < 4; ++r) {
                int m = m0 + r;
                int b = m >> tcs;
                int t = m & tcmask;
                int br = b >> 2, brow = b & 3;
                out[(((long)br * Tc + t) * 4 + bn) * 512 + brow * 128 + hid] =
                    acc[i][j][r] + bb;
            }
        }
    }
}

// ---------------------------------------------------------------------------
// Dual-role, two-set pipelined recurrence. 256 blocks x 512 threads.
// blocks 0-127: L0 producer; blocks 128-255: L1 consumer.
// Sets: P = rows 0-1 (waves 0-3 own ew), Q = rows 2-3 (waves 4-7).
// Segment = one barrier interval = MFMA(set A, t) || ew(set B, t').
// ---------------------------------------------------------------------------
#define BARRIER_()                                                             \
    do {                                                                       \
        asm volatile("s_waitcnt lgkmcnt(0)" ::: "memory");                     \
        __builtin_amdgcn_s_barrier();                                          \
        __builtin_amdgcn_sched_barrier(0);                                     \
    } while (0)

// Producer segment: MFMA(ACT, TM) -> gbuf[ACT]; ew(EWS, TE) w/ slot XS.
#define PSEG(ACT, TM, EWS, TE, XS, EWVALID)                                    \
    {                                                                          \
        bf16x8 a[4];                                                           \
        _Pragma("unroll")                                                      \
        for (int ks = 0; ks < 4; ++ks) {                                       \
            int ba = (col * 256 + ks * 64 + lgroup * 16) ^ ((col & 7) << 4);   \
            a[ks] = *(const bf16x8*)((const char*)h_lds + ba);                 \
        }                                                                      \
        __builtin_amdgcn_s_setprio(1);                                         \
        f32x4 acc[4];                                                          \
        _Pragma("unroll")                                                      \
        for (int g = 0; g < 4; ++g) acc[g] = (f32x4){0.f, 0.f, 0.f, 0.f};      \
        _Pragma("unroll")                                                      \
        for (int ks = 0; ks < 4; ++ks)                                         \
            _Pragma("unroll")                                                  \
            for (int g = 0; g < 4; ++g)                                        \
                acc[g] = __builtin_amdgcn_mfma_f32_16x16x32_bf16(              \
                    a[ks], __builtin_bit_cast(bf16x8, wreg[g][ks]), acc[g],    \
                    0, 0, 0);                                                  \
        __builtin_amdgcn_s_setprio(0);                                         \
        if (lgroup == 0) {                                                     \
            _Pragma("unroll")                                                  \
            for (int j = 0; j < 2; ++j) {                                      \
                int r = (ACT) * 2 + j;                                         \
                f32x4 v;                                                       \
                v[0] = acc[0][r]; v[1] = acc[1][r];                            \
                v[2] = acc[2][r]; v[3] = acc[3][r];                            \
                *(f32x4*)(gset[ACT] + j * 2048 + coff * 16) = v;               \
            }                                                                  \
        }                                                                      \
        if ((EWVALID) && myset == (EWS)) {                                     \
            f32x4 gv = *(const f32x4*)(gset[EWS] + uid * 16);                  \
            float zi = gv[0] + XS.x, zf = gv[1] + XS.y;                        \
            float zg = gv[2] + XS.z, zo = gv[3] + XS.w;                        \
            c = sigm(zf) * c + sigm(zi) * tanhfast(zg);                        \
            h = sigm(zo) * tanhfast(c);                                        \
            *(bf16_t*)((char*)h_lds + hba) = (bf16_t)h;                        \
            h0qp[(long)(TE) * 512] = (bf16_t)h;                                \
            if ((TE) + 2 < Tc) {                                               \
                long o = (long)((TE) + 2) * 2048;                              \
                XS.x = xpt[o];        XS.y = xpt[o + 512];                     \
                XS.z = xpt[o + 1024]; XS.w = xpt[o + 1536];                    \
            }                                                                  \
            if (((TE) & 15) == 15)                                             \
                asm volatile("s_waitcnt vmcnt(0)" ::: "memory");               \
        }                                                                      \
        BARRIER_();                                                            \
        if ((EWVALID) && (((TE) & 15) == 15) && tid == (EWS) * 256) {          \
            __threadfence();                                                   \
            __hip_atomic_store(flagp + (EWS) * NCH + subbase + ((TE) >> 4),    \
                               1u, __ATOMIC_RELEASE, __HIP_MEMORY_SCOPE_AGENT);\
        }                                                                      \
    }

// Consumer segment: optional DMA of set DS half-image at time DT; MFMA(ACT)
// = Wi1@h0stg + Wh1@h1_lds; ew(EWS, valid) with bias.
#define CSEG(ACT, EWS, EWVALID, DS, DT, DVALID)                                \
    {                                                                          \
        if ((DVALID) && wv == 0) {                                             \
            if (((DT) & 15) == 0) {                                            \
                unsigned* fp = flagp + (DS) * NCH + subbase + ((DT) >> 4);     \
                while (__hip_atomic_load(fp, __ATOMIC_ACQUIRE,                 \
                                         __HIP_MEMORY_SCOPE_AGENT) == 0u)      \
                    __builtin_amdgcn_s_sleep(2);                               \
            }                                                                  \
            if (l < 32)                                                        \
                __builtin_amdgcn_global_load_lds(                              \
                    (const __attribute__((address_space(1))) void*)(           \
                        h0q + ((long)pair * Tc + (DT)) * 512 + (DS) * 256      \
                        + l * 8),                                              \
                    (__attribute__((address_space(3))) void*)(                 \
                        h0stg + (DS) * 256), 16, 0, 0);                        \
        }                                                                      \
        bf16x8 a0[4], a1[4];                                                   \
        _Pragma("unroll")                                                      \
        for (int ks = 0; ks < 4; ++ks) {                                       \
            int ba = (col * 256 + ks * 64 + lgroup * 16) ^ ((col & 7) << 4);   \
            a0[ks] = *(const bf16x8*)((const char*)h0stg + ba);                \
            a1[ks] = *(const bf16x8*)((const char*)h1_lds + ba);               \
        }                                                                      \
        __builtin_amdgcn_s_setprio(1);                                         \
        f32x4 acc[4];                                                          \
        _Pragma("unroll")                                                      \
        for (int g = 0; g < 4; ++g) acc[g] = (f32x4){0.f, 0.f, 0.f, 0.f};      \
        _Pragma("unroll")                                                      \
        for (int ks = 0; ks < 4; ++ks)                                         \
            _Pragma("unroll")                                                  \
            for (int g = 0; g < 4; ++g)                                        \
                acc[g] = __builtin_amdgcn_mfma_f32_16x16x32_bf16(              \
                    a0[ks], __builtin_bit_cast(bf16x8, wI[g][ks]), acc[g],     \
                    0, 0, 0);                                                  \
        _Pragma("unroll")                                                      \
        for (int ks = 0; ks < 4; ++ks)                                         \
            _Pragma("unroll")                                                  \
            for (int g = 0; g < 4; ++g)                                        \
                acc[g] = __builtin_amdgcn_mfma_f32_16x16x32_bf16(              \
                    a1[ks], __builtin_bit_cast(bf16x8, wH[g][ks]), acc[g],     \
                    0, 0, 0);                                                  \
        __builtin_amdgcn_s_setprio(0);                                         \
        if (lgroup == 0) {                                                     \
            _Pragma("unroll")                                                  \
            for (int j = 0; j < 2; ++j) {                                      \
                int r = (ACT) * 2 + j;                                         \
                f32x4 v;                                                       \
                v[0] = acc[0][r]; v[1] = acc[1][r];                            \
                v[2] = acc[2][r]; v[3] = acc[3][r];                            \
                *(f32x4*)(gset[ACT] + j * 2048 + coff * 16) = v;               \
            }                                                                  \
        }                                                                      \
        if ((EWVALID) && myset == (EWS)) {                                     \
            f32x4 gv = *(const f32x4*)(gset[EWS] + uid * 16);                  \
            float zi = gv[0] + bias1.x, zf = gv[1] + bias1.y;                  \
            float zg = gv[2] + bias1.z, zo = gv[3] + bias1.w;                  \
            c = sigm(zf) * c + sigm(zi) * tanhfast(zg);                        \
            h = sigm(zo) * tanhfast(c);                                        \
            *(bf16_t*)((char*)h1_lds + hba) = (bf16_t)h;                       \
        }                                                                      \
        if (wv == 0)                                                           \
            asm volatile("s_waitcnt vmcnt(0)" ::: "memory");                   \
        BARRIER_();                                                            \
    }

__global__ __launch_bounds__(512, 2) void lstm_dual(
    const float* __restrict__ xp4,   // [B/4][Tc][4][512] layer-0 projection
    const bf16_t* __restrict__ Wh0,  // Whh0 bf16 [512][128]
    const bf16_t* __restrict__ Wi1,  // Wih1 bf16 [512][128]
    const bf16_t* __restrict__ Wh1,  // Whh1 bf16 [512][128]
    const float* __restrict__ bih1, const float* __restrict__ bhh1,
    bf16_t* __restrict__ h0q,        // [128][Tc][512] swizzled h0 images
    unsigned* __restrict__ flags,    // [128][2][NCH]
    float* __restrict__ h0st, float* __restrict__ c0st,
    float* __restrict__ h1st, float* __restrict__ c1st,
    int Tc, int first, int subbase)
{
    __shared__ __align__(16) char pool[16 * 1024];
    int tid = threadIdx.x;
    int l = tid & 63;
    int wv = tid >> 6;                // wave 0..7
    int pair = blockIdx.x & 127;
    int r0 = pair * RB;
    int col = l & 15;
    int lgroup = l >> 4;
    int kreg = lgroup * 8;
    int myset = wv >> 2;              // 0 = P-owner, 1 = Q-owner
    int uid = tid & 255;              // unit within set
    int erow = tid >> 7;              // 0..3 (= myset*2 + (uid>>7))
    int ehid = tid & 127;
    const int hba = (erow * 256 + ehid * 2) ^ ((erow & 7) << 4);
    unsigned* flagp = flags + pair * 2 * NCH;
    int coff = wv * 16 + col;

    if (blockIdx.x < 128) {
        // ================= producer: layer-0, two-set pipeline ===========
        bf16_t* h_lds = (bf16_t*)pool;                 // 4 KB
        char* gset[2] = { pool + 4096, pool + 8192 };  // 4 KB each

        f32x4 wreg[4][4];
        #pragma unroll
        for (int g = 0; g < 4; ++g)
            #pragma unroll
            for (int ks = 0; ks < 4; ++ks)
                wreg[g][ks] = *(const f32x4*)(Wh0 + (long)(g * 128 + coff) * HID
                                              + ks * 32 + kreg);
        #pragma unroll
        for (int g = 0; g < 4; ++g)
            #pragma unroll
            for (int ks = 0; ks < 4; ++ks)
                asm volatile("" : "+a"(wreg[g][ks]));

        float c = first ? 0.f : c0st[(r0 + erow) * HID + ehid];
        float h = first ? 0.f : h0st[(r0 + erow) * HID + ehid];

        ((float2*)h_lds)[tid & 255] = make_float2(0.f, 0.f);
        __syncthreads();
        *(bf16_t*)((char*)h_lds + hba) = (bf16_t)h;
        __syncthreads();

        const float* xpt = xp4 + (long)pair * Tc * 2048 + tid;
        bf16_t* h0qp = h0q + (long)pair * Tc * 512 + (hba >> 1);
        float4 xA, xB;
        xA.x = xpt[0];    xA.y = xpt[512];
        xA.z = xpt[1024]; xA.w = xpt[1536];
        if (Tc > 1) {
            xB.x = xpt[2048];        xB.y = xpt[2048 + 512];
            xB.z = xpt[2048 + 1024]; xB.w = xpt[2048 + 1536];
        } else {
            xB = make_float4(0.f, 0.f, 0.f, 0.f);
        }

        for (int tt = 0; tt < Tc; tt += 2) {
            PSEG(0, tt,     1, tt - 1, xB, tt > 0)   // MFMA(P,tt)   | ew(Q,tt-1)
            PSEG(1, tt,     0, tt,     xA, 1)        // MFMA(Q,tt)   | ew(P,tt)
            PSEG(0, tt + 1, 1, tt,     xA, 1)        // MFMA(P,tt+1) | ew(Q,tt)
            PSEG(1, tt + 1, 0, tt + 1, xB, 1)        // MFMA(Q,tt+1) | ew(P,tt+1)
        }
        // epilogue: ew(Q, Tc-1)
        {
            if (myset == 1) {
                f32x4 gv = *(const f32x4*)(gset[1] + uid * 16);
                float zi = gv[0] + xB.x, zf = gv[1] + xB.y;
                float zg = gv[2] + xB.z, zo = gv[3] + xB.w;
                c = sigm(zf) * c + sigm(zi) * tanhfast(zg);
                h = sigm(zo) * tanhfast(c);
                h0qp[(long)(Tc - 1) * 512] = (bf16_t)h;
                asm volatile("s_waitcnt vmcnt(0)" ::: "memory");
            }
            BARRIER_();
            if (tid == 256) {
                __threadfence();
                __hip_atomic_store(flagp + NCH + subbase + ((Tc - 1) >> 4), 1u,
                                   __ATOMIC_RELEASE, __HIP_MEMORY_SCOPE_AGENT);
            }
        }

        h0st[(r0 + erow) * HID + ehid] = h;
        c0st[(r0 + erow) * HID + ehid] = c;
    } else {
        // ================= consumer: layer-1, two-set pipeline ===========
        bf16_t* h0stg  = (bf16_t*)pool;                   // 4 KB tile
        bf16_t* h1_lds = (bf16_t*)(pool + 4096);          // 4 KB
        char* gset[2] = { pool + 8192, pool + 12288 };    // 4 KB each

        f32x4 wI[4][4], wH[4][4];
        #pragma unroll
        for (int g = 0; g < 4; ++g)
            #pragma unroll
            for (int ks = 0; ks < 4; ++ks) {
                long o = (long)(g * 128 + coff) * HID + ks * 32 + kreg;
                wI[g][ks] = *(const f32x4*)(Wi1 + o);
                wH[g][ks] = *(const f32x4*)(Wh1 + o);
            }
        #pragma unroll
        for (int g = 0; g < 4; ++g)
            #pragma unroll
            for (int ks = 0; ks < 4; ++ks) {
                asm volatile("" : "+a"(wI[g][ks]));
                asm volatile("" : "+a"(wH[g][ks]));
            }

        float4 bias1;
        bias1.x = bih1[ehid]       + bhh1[ehid];
        bias1.y = bih1[128 + ehid] + bhh1[128 + ehid];
        bias1.z = bih1[256 + ehid] + bhh1[256 + ehid];
        bias1.w = bih1[384 + ehid] + bhh1[384 + ehid];

        float c = first ? 0.f : c1st[(r0 + erow) * HID + ehid];
        float h = first ? 0.f : h1st[(r0 + erow) * HID + ehid];

        // zero h0stg + h1_lds (8 KB)
        ((float2*)pool)[tid] = make_float2(0.f, 0.f);
        ((float2*)pool)[tid + 512] = make_float2(0.f, 0.f);
        __syncthreads();
        *(bf16_t*)((char*)h1_lds + hba) = (bf16_t)h;
        __syncthreads();

        // prestage full image 0 (P then Q flags; Q posted 1 seg after P)
        if (wv == 0) {
            unsigned* fp0 = flagp + subbase;
            while (__hip_atomic_load(fp0, __ATOMIC_ACQUIRE,
                                     __HIP_MEMORY_SCOPE_AGENT) == 0u)
                __builtin_amdgcn_s_sleep(2);
            unsigned* fp1 = flagp + NCH + subbase;
            while (__hip_atomic_load(fp1, __ATOMIC_ACQUIRE,
                                     __HIP_MEMORY_SCOPE_AGENT) == 0u)
                __builtin_amdgcn_s_sleep(2);
            __builtin_amdgcn_global_load_lds(
                (const __attribute__((address_space(1))) void*)(
                    h0q + (long)pair * Tc * 512 + l * 8),
                (__attribute__((address_space(3))) void*)h0stg, 16, 0, 0);
            asm volatile("s_waitcnt vmcnt(0)" ::: "memory");
        }
        __syncthreads();

        for (int tt = 0; tt < Tc; tt += 2) {
            CSEG(0, 1, tt > 0, 1, tt,     tt > 0)       // MFMA(P,tt)  |ew(Q,tt-1)|DMA Q[tt]
            CSEG(1, 0, 1,      0, tt + 1, tt + 1 < Tc)  // MFMA(Q,tt)  |ew(P,tt)  |DMA P[tt+1]
            CSEG(0, 1, 1,      1, tt + 1, 1)            // MFMA(P,tt+1)|ew(Q,tt)  |DMA Q[tt+1]
            CSEG(1, 0, 1,      0, tt + 2, tt + 2 < Tc)  // MFMA(Q,tt+1)|ew(P,tt+1)|DMA P[tt+2]
        }
        // epilogue: ew(Q, Tc-1)
        if (myset == 1) {
            f32x4 gv = *(const f32x4*)(gset[1] + uid * 16);
            float zi = gv[0] + bias1.x, zf = gv[1] + bias1.y;
            float zg = gv[2] + bias1.z, zo = gv[3] + bias1.w;
            c = sigm(zf) * c + sigm(zi) * tanhfast(zg);
            h = sigm(zo) * tanhfast(c);
        }

        h1st[(r0 + erow) * HID + ehid] = h;
        c1st[(r0 + erow) * HID + ehid] = c;
    }
}

// ---------------------------------------------------------------------------
// FC head + softmax + state copy-out. One block per batch row, 128 threads.
// out layout: probs [512*10] | h_n [2*512*128] | c_n [2*512*128]
// ---------------------------------------------------------------------------
__global__ __launch_bounds__(128) void fc_head(
    const float* __restrict__ h0st, const float* __restrict__ c0st,
    const float* __restrict__ h1st, const float* __restrict__ c1st,
    const float* __restrict__ fc1w, const float* __restrict__ fc1b,
    const float* __restrict__ fc2w, const float* __restrict__ fc2b,
    float* __restrict__ out)
{
    __shared__ float h1_s[HID];
    __shared__ float hid_s[64];
    __shared__ float log_s[10];
    int t = threadIdx.x;
    int b = blockIdx.x;

    h1_s[t] = h1st[b * HID + t];
    __syncthreads();

    if (t < 64) {
        float a = fc1b[t];
        const float* wrow = fc1w + t * HID;
        #pragma unroll 4
        for (int k = 0; k < HID; ++k) a = fmaf(wrow[k], h1_s[k], a);
        hid_s[t] = fmaxf(a, 0.f);
    }
    __syncthreads();

    if (t < 10) {
        float a = fc2b[t];
        const float* wrow = fc2w + t * 64;
        #pragma unroll 4
        for (int k = 0; k < 64; ++k) a = fmaf(wrow[k], hid_s[k], a);
        log_s[t] = a;
    }
    __syncthreads();

    if (t == 0) {
        float m = log_s[0];
        #pragma unroll
        for (int j = 1; j < 10; ++j) m = fmaxf(m, log_s[j]);
        float e[10];
        float s = 0.f;
        #pragma unroll
        for (int j = 0; j < 10; ++j) { e[j] = __expf(log_s[j] - m); s += e[j]; }
        float inv = __builtin_amdgcn_rcpf(s);
        #pragma unroll
        for (int j = 0; j < 10; ++j) out[b * 10 + j] = e[j] * inv;
    }

    float* hn = out + BATCH * 10;
    float* cn = hn + 2 * BATCH * HID;
    hn[b * HID + t] = h0st[b * HID + t];
    hn[BATCH * HID + b * HID + t] = h1_s[t];
    cn[b * HID + t] = c0st[b * HID + t];
    cn[BATCH * HID + b * HID + t] = c1st[b * HID + t];
}

// ---------------------------------------------------------------------------
extern "C" void kernel_launch(void* const* d_in, const int* in_sizes, int n_in,
                              void* d_out, int out_size, void* d_ws, size_t ws_size,
                              hipStream_t stream) {
    const float* x    = (const float*)d_in[0];
    const float* Wih0 = (const float*)d_in[1];
    const float* Whh0 = (const float*)d_in[2];
    const float* bih0 = (const float*)d_in[3];
    const float* bhh0 = (const float*)d_in[4];
    const float* Wih1 = (const float*)d_in[5];
    const float* Whh1 = (const float*)d_in[6];
    const float* bih1 = (const float*)d_in[7];
    const float* bhh1 = (const float*)d_in[8];
    const float* fc1w = (const float*)d_in[9];
    const float* fc1b = (const float*)d_in[10];
    const float* fc2w = (const float*)d_in[11];
    const float* fc2b = (const float*)d_in[12];
    float* out = (float*)d_out;

    int Tc = SEQT;
    while (Tc > SUBS) {
        size_t need = (size_t)BATCH * Tc * GATES * 4        // xp4
                    + (size_t)BATCH * SEQT * INPUTD * 2     // xb
                    + ((size_t)GATES * INPUTD + 3 * (size_t)GATES * HID) * 2
                    + (size_t)128 * Tc * 512 * 2            // h0q
                    + 4 * (size_t)BATCH * HID * 4
                    + 128 * 2 * NCH * 4 + 512;
        if (need <= ws_size) break;
        Tc >>= 1;
    }
    int tcs = __builtin_ctz((unsigned)Tc);

    float*    xp   = (float*)d_ws;
    bf16_t*   xb   = (bf16_t*)(xp + (size_t)BATCH * Tc * GATES);
    bf16_t*   wb0  = xb + (size_t)BATCH * SEQT * INPUTD;
    bf16_t*   wb1  = wb0 + (size_t)GATES * INPUTD;
    bf16_t*   wh0b = wb1 + (size_t)GATES * HID;
    bf16_t*   wh1b = wh0b + (size_t)GATES * HID;
    bf16_t*   h0q  = wh1b + (size_t)GATES * HID;
    float*    h0st = (float*)(h0q + (size_t)128 * Tc * 512);
    float*    c0st = h0st + (size_t)BATCH * HID;
    float*    h1st = c0st + (size_t)BATCH * HID;
    float*    c1st = h1st + (size_t)BATCH * HID;
    unsigned* flags = (unsigned*)(c1st + (size_t)BATCH * HID);

    // flags MUST be re-zeroed every call (graph replays don't re-poison)
    hipMemsetAsync(flags, 0, 128 * 2 * NCH * sizeof(unsigned), stream);

    cvt_f32_bf16<<<2048, 256, 0, stream>>>(x, xb, (long)BATCH * SEQT * INPUTD / 4);
    cvt_weights<<<448, 256, 0, stream>>>(Wih0, Wih1, Whh0, Whh1,
                                         wb0, wb1, wh0b, wh1b);

    int nchunk = SEQT / Tc;
    dim3 gemm_grid(GATES / 128, (BATCH * Tc) / 128);

    for (int ci = 0; ci < nchunk; ++ci) {
        gemm_mfma<<<gemm_grid, 256, 0, stream>>>(
            xb, wb0, bih0, bhh0, xp, INPUTD, tcs, Tc - 1, SEQT, ci * Tc);
        lstm_dual<<<256, 512, 0, stream>>>(
            xp, wh0b, wb1, wh1b, bih1, bhh1, h0q, flags,
            h0st, c0st, h1st, c1st, Tc, ci == 0, ci * (Tc / SUBS));
    }

    fc_head<<<BATCH, 128, 0, stream>>>(
        h0st, c0st, h1st, c1st, fc1w, fc1b, fc2w, fc2b, out);
}

// Round 16
// 586.691 us; speedup vs baseline: 1.3726x; 1.3726x over previous
//
#include <hip/hip_runtime.h>
#include <hip/hip_bf16.h>

// ---------------------------------------------------------------------------
// RecurrentBattleNet: 2-layer LSTM (B=512, T=256, IN=512, H=128) + FC head.
// Round 16: REVERT dual to R14 (R15's two-set pipeline doubled MFMA issue:
// full 16-row tile computed per segment for one 2-row set -> 2x wave-MFMA
// +3x bank conflicts; 381->602us). Trims kept/added: cvt_x FUSED into the
// GEMM (reg-staged A with in-register f32->bf16), merged cvt_weights with
// flags-zeroing block (2 fewer dispatches).
// ---------------------------------------------------------------------------

#define BATCH 512
#define SEQT  256
#define INPUTD 512
#define HID   128
#define GATES 512   // 4*HID
#define RB    4     // batch rows per recurrence block
#define SUBS  16    // producer->consumer flag granularity (steps)
#define NCH   (SEQT / SUBS)

typedef __bf16 bf16_t;
typedef bf16_t bf16x4 __attribute__((ext_vector_type(4)));
typedef bf16_t bf16x8 __attribute__((ext_vector_type(8)));
typedef float  f32x4  __attribute__((ext_vector_type(4)));

__device__ __forceinline__ float sigm(float x) {
    return __builtin_amdgcn_rcpf(1.f + __expf(-x));
}
__device__ __forceinline__ float tanhfast(float x) {
    float xc = fminf(fmaxf(x, -15.f), 15.f);
    float e = __expf(2.f * xc);
    return (e - 1.f) * __builtin_amdgcn_rcpf(e + 1.f);
}

// ---------------------------------------------------------------------------
// Weights f32->bf16 (4 matrices) in one launch; block 448 zeroes the flags.
// ---------------------------------------------------------------------------
__global__ __launch_bounds__(256) void cvt_weights(
    const float* __restrict__ w0, const float* __restrict__ w1,
    const float* __restrict__ w2, const float* __restrict__ w3,
    bf16_t* __restrict__ o0, bf16_t* __restrict__ o1,
    bf16_t* __restrict__ o2, bf16_t* __restrict__ o3,
    unsigned* __restrict__ flags)
{
    int b = blockIdx.x;
    if (b == 448) {
        // zero 128*2*NCH = 4096 unsigneds (16 KB)
        uint4 z = make_uint4(0u, 0u, 0u, 0u);
        #pragma unroll
        for (int i = 0; i < 4; ++i)
            ((uint4*)flags)[i * 256 + threadIdx.x] = z;
        return;
    }
    const float* src; bf16_t* dst; long base;
    if (b < 256)      { src = w0; dst = o0; base = (long)b * 256; }
    else if (b < 320) { src = w1; dst = o1; base = (long)(b - 256) * 256; }
    else if (b < 384) { src = w2; dst = o2; base = (long)(b - 320) * 256; }
    else              { src = w3; dst = o3; base = (long)(b - 384) * 256; }
    long i = base + threadIdx.x;
    float4 v = ((const float4*)src)[i];
    bf16x4 r;
    r[0] = (bf16_t)v.x; r[1] = (bf16_t)v.y;
    r[2] = (bf16_t)v.z; r[3] = (bf16_t)v.w;
    ((bf16x4*)dst)[i] = r;
}

// ---------------------------------------------------------------------------
// bf16 MFMA GEMM (layer-0 input projection), A read as f32 with in-register
// cvt (fuses the x conversion). Writes gate-major xp:
//   xp4[b>>2][t][gate][(b&3)*128 + hid]   (float)
// A-side: logical row m -> physical row (m>>tcs)*srcT + t0 + (m&tcmask).
// 128x128 tile, BK=32, 256 thr (4 waves 2x2), 16x16x32 MFMA. bn == gate.
// ---------------------------------------------------------------------------
__global__ __launch_bounds__(256) void gemm_mfma(
    const float* __restrict__ A, const bf16_t* __restrict__ W,
    const float* __restrict__ b1, const float* __restrict__ b2,
    float* __restrict__ out,
    int K, int tcs, int tcmask, int srcT, int t0)
{
    __shared__ bf16_t As[128 * 32];
    __shared__ bf16_t Bs[128 * 32];
    int tid = threadIdx.x;
    int l = tid & 63;
    int w = tid >> 6;
    int wm = w >> 1, wn = w & 1;
    int bn = blockIdx.x;
    int bm = blockIdx.y;
    int Tc = tcmask + 1;

    long aoff[2], boff[2];
    #pragma unroll
    for (int c = 0; c < 2; ++c) {
        int m = bm * 128 + (tid >> 2) + 64 * c;
        int xr = ((m >> tcs) * srcT) + t0 + (m & tcmask);
        aoff[c] = (long)xr * K + (tid & 3) * 8;
        int n = bn * 128 + (tid >> 2) + 64 * c;
        boff[c] = (long)n * K + (tid & 3) * 8;
    }

    f32x4 acc[4][4];
    #pragma unroll
    for (int i = 0; i < 4; ++i)
        #pragma unroll
        for (int j = 0; j < 4; ++j)
            acc[i][j] = (f32x4){0.f, 0.f, 0.f, 0.f};

    const int rbase = wm * 64 + (l & 15);
    const int cbase = wn * 64 + (l & 15);
    const int kfrag = (l >> 4) * 8;

    for (int kt = 0; kt < K; kt += 32) {
        // A: reg-stage f32 -> cvt -> LDS (fused x conversion)
        float4 av[2][2];
        #pragma unroll
        for (int c = 0; c < 2; ++c) {
            av[c][0] = *(const float4*)(A + aoff[c] + kt);
            av[c][1] = *(const float4*)(A + aoff[c] + kt + 4);
        }
        // B: direct global->LDS DMA (bf16 weights)
        __builtin_amdgcn_global_load_lds(
            (const __attribute__((address_space(1))) void*)(W + boff[0] + kt),
            (__attribute__((address_space(3))) void*)(Bs + tid * 8), 16, 0, 0);
        __builtin_amdgcn_global_load_lds(
            (const __attribute__((address_space(1))) void*)(W + boff[1] + kt),
            (__attribute__((address_space(3))) void*)(Bs + 2048 + tid * 8), 16, 0, 0);
        #pragma unroll
        for (int c = 0; c < 2; ++c) {
            bf16x8 ab;
            ab[0] = (bf16_t)av[c][0].x; ab[1] = (bf16_t)av[c][0].y;
            ab[2] = (bf16_t)av[c][0].z; ab[3] = (bf16_t)av[c][0].w;
            ab[4] = (bf16_t)av[c][1].x; ab[5] = (bf16_t)av[c][1].y;
            ab[6] = (bf16_t)av[c][1].z; ab[7] = (bf16_t)av[c][1].w;
            *(bf16x8*)(As + c * 2048 + tid * 8) = ab;
        }
        __syncthreads();

        bf16x8 af[4], bfr[4];
        #pragma unroll
        for (int i = 0; i < 4; ++i)
            af[i] = *(const bf16x8*)(As + (rbase + i * 16) * 32 + kfrag);
        #pragma unroll
        for (int j = 0; j < 4; ++j)
            bfr[j] = *(const bf16x8*)(Bs + (cbase + j * 16) * 32 + kfrag);

        #pragma unroll
        for (int i = 0; i < 4; ++i)
            #pragma unroll
            for (int j = 0; j < 4; ++j)
                acc[i][j] = __builtin_amdgcn_mfma_f32_16x16x32_bf16(
                    af[i], bfr[j], acc[i][j], 0, 0, 0);
        __syncthreads();
    }

    #pragma unroll
    for (int i = 0; i < 4; ++i) {
        int m0 = bm * 128 + wm * 64 + i * 16 + (l >> 4) * 4;
        #pragma unroll
        for (int j = 0; j < 4; ++j) {
            int n = bn * 128 + wn * 64 + j * 16 + (l & 15);
            float bb = b1[n] + b2[n];
            int hid = n & 127;          // g == bn
            #pragma unroll
            for (int r = 0; r < 4; ++r) {
                int m = m0 + r;
                int b = m >> tcs;
                int t = m & tcmask;
                int br = b >> 2, brow = b & 3;
                out[(((long)br * Tc + t) * 4 + bn) * 512 + brow * 128 + hid] =
                    acc[i][j][r] + bb;
            }
        }
    }
}

// ---------------------------------------------------------------------------
// Dual-role recurrence kernel (R14-proven). 256 blocks x 512 threads.
//   blocks 0-127  : layer-0 recurrence (producer)
//   blocks 128-255: layer-1 recurrence (consumer)
// ---------------------------------------------------------------------------
#define BARRIER_()                                                             \
    do {                                                                       \
        asm volatile("s_waitcnt lgkmcnt(0)" ::: "memory");                     \
        __builtin_amdgcn_s_barrier();                                          \
        __builtin_amdgcn_sched_barrier(0);                                     \
    } while (0)

#define REC0_STEP(X, t)                                                        \
    {                                                                          \
        bf16x8 a[4];                                                           \
        _Pragma("unroll")                                                      \
        for (int ks = 0; ks < 4; ++ks) {                                       \
            int ba = (col * 256 + ks * 64 + lgroup * 16) ^ ((col & 7) << 4);   \
            a[ks] = *(const bf16x8*)((const char*)h_lds + ba);                 \
        }                                                                      \
        f32x4 acc[4];                                                          \
        _Pragma("unroll")                                                      \
        for (int g = 0; g < 4; ++g) acc[g] = (f32x4){0.f, 0.f, 0.f, 0.f};      \
        _Pragma("unroll")                                                      \
        for (int ks = 0; ks < 4; ++ks)                                         \
            _Pragma("unroll")                                                  \
            for (int g = 0; g < 4; ++g)                                        \
                acc[g] = __builtin_amdgcn_mfma_f32_16x16x32_bf16(              \
                    a[ks], __builtin_bit_cast(bf16x8, wreg[g][ks]), acc[g],    \
                    0, 0, 0);                                                  \
        if (lgroup == 0) {                                                     \
            _Pragma("unroll")                                                  \
            for (int r = 0; r < 4; ++r) {                                      \
                f32x4 v;                                                       \
                v[0] = acc[0][r]; v[1] = acc[1][r];                            \
                v[2] = acc[2][r]; v[3] = acc[3][r];                            \
                *(f32x4*)((char*)g_lds + r * 2048 + coff * 16) = v;            \
            }                                                                  \
        }                                                                      \
        BARRIER_();                                                            \
        {                                                                      \
            f32x4 gv = *(const f32x4*)((const char*)g_lds + tid * 16);         \
            float zi = gv[0] + X.x, zf = gv[1] + X.y;                          \
            float zg = gv[2] + X.z, zo = gv[3] + X.w;                          \
            c = sigm(zf) * c + sigm(zi) * tanhfast(zg);                        \
            h = sigm(zo) * tanhfast(c);                                        \
            *(bf16_t*)((char*)h_lds + hba) = (bf16_t)h;                        \
            h0qp[(long)(t) * 512] = (bf16_t)h;                                 \
        }                                                                      \
        if ((t) + 2 < Tc) {                                                    \
            long o = (long)((t) + 2) * 2048;                                   \
            X.x = xpt[o];        X.y = xpt[o + 512];                           \
            X.z = xpt[o + 1024]; X.w = xpt[o + 1536];                          \
        }                                                                      \
        if (((t) & (SUBS - 1)) == SUBS - 1)                                    \
            asm volatile("s_waitcnt vmcnt(0)" ::: "memory");                   \
        BARRIER_();                                                            \
        if ((((t) & (SUBS - 1)) == SUBS - 1) && tid == 0) {                    \
            __threadfence();                                                   \
            __hip_atomic_store(flagp + ((t) >> 4), 1u, __ATOMIC_RELEASE,       \
                               __HIP_MEMORY_SCOPE_AGENT);                      \
        }                                                                      \
    }

__global__ __launch_bounds__(512, 2) void lstm_dual(
    const float* __restrict__ xp4,   // [B/4][Tc][4][512] layer-0 projection
    const bf16_t* __restrict__ Wh0,  // Whh0 bf16 [512][128]
    const bf16_t* __restrict__ Wi1,  // Wih1 bf16 [512][128]
    const bf16_t* __restrict__ Wh1,  // Whh1 bf16 [512][128]
    const float* __restrict__ bih1, const float* __restrict__ bhh1,
    bf16_t* __restrict__ h0q,        // [128][Tc][512] swizzled h0 images
    unsigned* __restrict__ flags,    // [128][NCH]
    float* __restrict__ h0st, float* __restrict__ c0st,
    float* __restrict__ h1st, float* __restrict__ c1st,
    int Tc, int first, int subbase)
{
    __shared__ __align__(16) char pool[28 * 1024];
    int tid = threadIdx.x;
    int l = tid & 63;
    int wv = tid >> 6;                // wave 0..7
    int pair = blockIdx.x & 127;
    int r0 = pair * RB;
    int col = l & 15;
    int lgroup = l >> 4;              // 0..3
    int kreg = lgroup * 8;
    int erow = tid >> 7, ehid = tid & 127;
    const int hba = (erow * 256 + ehid * 2) ^ ((erow & 7) << 4);
    unsigned* flagp = flags + pair * NCH + subbase;

    if (blockIdx.x < 128) {
        // ================= producer: layer-0 recurrence =================
        bf16_t* h_lds = (bf16_t*)pool;           // 4 KB (16 rows, swizzled)
        float*  g_lds = (float*)(pool + 4096);   // 8 KB
        int coff = wv * 16 + col;                // owned gate-col

        f32x4 wreg[4][4];
        #pragma unroll
        for (int g = 0; g < 4; ++g)
            #pragma unroll
            for (int ks = 0; ks < 4; ++ks)
                wreg[g][ks] = *(const f32x4*)(Wh0 + (long)(g * 128 + coff) * HID
                                              + ks * 32 + kreg);
        #pragma unroll
        for (int g = 0; g < 4; ++g)
            #pragma unroll
            for (int ks = 0; ks < 4; ++ks)
                asm volatile("" : "+a"(wreg[g][ks]));

        float c = first ? 0.f : c0st[(r0 + erow) * HID + ehid];
        float h = first ? 0.f : h0st[(r0 + erow) * HID + ehid];

        ((float2*)h_lds)[tid & 255] = make_float2(0.f, 0.f);   // zero 4 KB
        __syncthreads();
        *(bf16_t*)((char*)h_lds + hba) = (bf16_t)h;
        __syncthreads();

        const float* xpt = xp4 + (long)pair * Tc * 2048 + tid;
        bf16_t* h0qp = h0q + (long)pair * Tc * 512 + (hba >> 1);
        float4 xA, xB;
        xA.x = xpt[0];    xA.y = xpt[512];
        xA.z = xpt[1024]; xA.w = xpt[1536];
        if (Tc > 1) {
            xB.x = xpt[2048];        xB.y = xpt[2048 + 512];
            xB.z = xpt[2048 + 1024]; xB.w = xpt[2048 + 1536];
        } else {
            xB = make_float4(0.f, 0.f, 0.f, 0.f);
        }

        for (int tt = 0; tt < Tc; tt += 2) {
            REC0_STEP(xA, tt)
            REC0_STEP(xB, tt + 1)
        }

        h0st[(r0 + erow) * HID + ehid] = h;
        c0st[(r0 + erow) * HID + ehid] = c;
    } else {
        // ================= consumer: layer-1 recurrence =================
        bf16_t* h0stg = (bf16_t*)pool;             // 2 x 4 KB images
        bf16_t* h1_lds = (bf16_t*)(pool + 8192);   // 4 KB
        float*  g1a = (float*)(pool + 12288);      // 8 KB (Wi1@h0 partial)
        float*  g1b = (float*)(pool + 20480);      // 8 KB (Wh1@h1 partial)
        int isWi = wv < 4;
        int w4 = wv & 3;                           // wave-within-role
        int coff1 = w4 * 32;                       // owned 32-col base

        const bf16_t* Wsrc = isWi ? Wi1 : Wh1;
        f32x4 wreg[2][4][4];
        #pragma unroll
        for (int c2 = 0; c2 < 2; ++c2)
            #pragma unroll
            for (int g = 0; g < 4; ++g)
                #pragma unroll
                for (int ks = 0; ks < 4; ++ks)
                    wreg[c2][g][ks] = *(const f32x4*)(
                        Wsrc + (long)(g * 128 + coff1 + c2 * 16 + col) * HID
                        + ks * 32 + kreg);
        #pragma unroll
        for (int c2 = 0; c2 < 2; ++c2)
            #pragma unroll
            for (int g = 0; g < 4; ++g)
                #pragma unroll
                for (int ks = 0; ks < 4; ++ks)
                    asm volatile("" : "+a"(wreg[c2][g][ks]));

        float4 bias1;
        bias1.x = bih1[ehid]       + bhh1[ehid];
        bias1.y = bih1[128 + ehid] + bhh1[128 + ehid];
        bias1.z = bih1[256 + ehid] + bhh1[256 + ehid];
        bias1.w = bih1[384 + ehid] + bhh1[384 + ehid];

        float c1 = first ? 0.f : c1st[(r0 + erow) * HID + ehid];
        float h1 = first ? 0.f : h1st[(r0 + erow) * HID + ehid];

        // zero h0stg (8 KB) + h1_lds (4 KB)
        ((float2*)pool)[tid] = make_float2(0.f, 0.f);
        ((float2*)pool)[tid + 512] = make_float2(0.f, 0.f);
        ((float2*)(pool + 8192))[tid & 255] = make_float2(0.f, 0.f);
        __syncthreads();
        *(bf16_t*)((char*)h1_lds + hba) = (bf16_t)h1;
        __syncthreads();

        // initial: wait chunk 0, DMA h0 image t=0 into h0stg[0]
        if (wv == 0) {
            while (__hip_atomic_load(flagp, __ATOMIC_ACQUIRE,
                                     __HIP_MEMORY_SCOPE_AGENT) == 0u)
                __builtin_amdgcn_s_sleep(2);
            __builtin_amdgcn_global_load_lds(
                (const __attribute__((address_space(1))) void*)(
                    h0q + (long)pair * Tc * 512 + l * 8),
                (__attribute__((address_space(3))) void*)h0stg, 16, 0, 0);
            asm volatile("s_waitcnt vmcnt(0)" ::: "memory");
        }
        __syncthreads();

        for (int t = 0; t < Tc; ++t) {
            int pw = (t + 1) & 3;        // prefetch-duty wave (a Wi-wave)
            if (t + 1 < Tc && wv == pw) {
                if (((t + 1) & (SUBS - 1)) == 0) {
                    unsigned* fp = flagp + ((t + 1) >> 4);
                    while (__hip_atomic_load(fp, __ATOMIC_ACQUIRE,
                                             __HIP_MEMORY_SCOPE_AGENT) == 0u)
                        __builtin_amdgcn_s_sleep(2);
                }
                __builtin_amdgcn_global_load_lds(
                    (const __attribute__((address_space(1))) void*)(
                        h0q + ((long)pair * Tc + t + 1) * 512 + l * 8),
                    (__attribute__((address_space(3))) void*)(
                        h0stg + ((t + 1) & 1) * 2048), 16, 0, 0);
            }

            // phase A: partial gates
            const char* asrc = isWi
                ? (const char*)(h0stg + (t & 1) * 2048)
                : (const char*)h1_lds;
            bf16x8 a[4];
            #pragma unroll
            for (int ks = 0; ks < 4; ++ks) {
                int ba = (col * 256 + ks * 64 + lgroup * 16) ^ ((col & 7) << 4);
                a[ks] = *(const bf16x8*)(asrc + ba);
            }
            float* gdst = isWi ? g1a : g1b;
            #pragma unroll
            for (int c2 = 0; c2 < 2; ++c2) {
                f32x4 acc[4];
                #pragma unroll
                for (int g = 0; g < 4; ++g) acc[g] = (f32x4){0.f, 0.f, 0.f, 0.f};
                #pragma unroll
                for (int ks = 0; ks < 4; ++ks)
                    #pragma unroll
                    for (int g = 0; g < 4; ++g)
                        acc[g] = __builtin_amdgcn_mfma_f32_16x16x32_bf16(
                            a[ks], __builtin_bit_cast(bf16x8, wreg[c2][g][ks]),
                            acc[g], 0, 0, 0);
                if (lgroup == 0) {
                    #pragma unroll
                    for (int r = 0; r < 4; ++r) {
                        f32x4 v;
                        v[0] = acc[0][r]; v[1] = acc[1][r];
                        v[2] = acc[2][r]; v[3] = acc[3][r];
                        *(f32x4*)((char*)gdst + r * 2048 +
                                  (coff1 + c2 * 16 + col) * 16) = v;
                    }
                }
            }
            BARRIER_();

            // phase B: ew (sum partials + bias)
            {
                f32x4 gva = *(const f32x4*)((const char*)g1a + tid * 16);
                f32x4 gvb = *(const f32x4*)((const char*)g1b + tid * 16);
                float zi = gva[0] + gvb[0] + bias1.x;
                float zf = gva[1] + gvb[1] + bias1.y;
                float zg = gva[2] + gvb[2] + bias1.z;
                float zo = gva[3] + gvb[3] + bias1.w;
                c1 = sigm(zf) * c1 + sigm(zi) * tanhfast(zg);
                h1 = sigm(zo) * tanhfast(c1);
                *(bf16_t*)((char*)h1_lds + hba) = (bf16_t)h1;
            }
            if (t + 1 < Tc && wv == pw)
                asm volatile("s_waitcnt vmcnt(0)" ::: "memory");
            BARRIER_();
        }

        h1st[(r0 + erow) * HID + ehid] = h1;
        c1st[(r0 + erow) * HID + ehid] = c1;
    }
}

// ---------------------------------------------------------------------------
// FC head + softmax + state copy-out. One block per batch row, 128 threads.
// out layout: probs [512*10] | h_n [2*512*128] | c_n [2*512*128]
// ---------------------------------------------------------------------------
__global__ __launch_bounds__(128) void fc_head(
    const float* __restrict__ h0st, const float* __restrict__ c0st,
    const float* __restrict__ h1st, const float* __restrict__ c1st,
    const float* __restrict__ fc1w, const float* __restrict__ fc1b,
    const float* __restrict__ fc2w, const float* __restrict__ fc2b,
    float* __restrict__ out)
{
    __shared__ float h1_s[HID];
    __shared__ float hid_s[64];
    __shared__ float log_s[10];
    int t = threadIdx.x;
    int b = blockIdx.x;

    h1_s[t] = h1st[b * HID + t];
    __syncthreads();

    if (t < 64) {
        float a = fc1b[t];
        const float* wrow = fc1w + t * HID;
        #pragma unroll 4
        for (int k = 0; k < HID; ++k) a = fmaf(wrow[k], h1_s[k], a);
        hid_s[t] = fmaxf(a, 0.f);
    }
    __syncthreads();

    if (t < 10) {
        float a = fc2b[t];
        const float* wrow = fc2w + t * 64;
        #pragma unroll 4
        for (int k = 0; k < 64; ++k) a = fmaf(wrow[k], hid_s[k], a);
        log_s[t] = a;
    }
    __syncthreads();

    if (t == 0) {
        float m = log_s[0];
        #pragma unroll
        for (int j = 1; j < 10; ++j) m = fmaxf(m, log_s[j]);
        float e[10];
        float s = 0.f;
        #pragma unroll
        for (int j = 0; j < 10; ++j) { e[j] = __expf(log_s[j] - m); s += e[j]; }
        float inv = __builtin_amdgcn_rcpf(s);
        #pragma unroll
        for (int j = 0; j < 10; ++j) out[b * 10 + j] = e[j] * inv;
    }

    float* hn = out + BATCH * 10;
    float* cn = hn + 2 * BATCH * HID;
    hn[b * HID + t] = h0st[b * HID + t];
    hn[BATCH * HID + b * HID + t] = h1_s[t];
    cn[b * HID + t] = c0st[b * HID + t];
    cn[BATCH * HID + b * HID + t] = c1st[b * HID + t];
}

// ---------------------------------------------------------------------------
extern "C" void kernel_launch(void* const* d_in, const int* in_sizes, int n_in,
                              void* d_out, int out_size, void* d_ws, size_t ws_size,
                              hipStream_t stream) {
    const float* x    = (const float*)d_in[0];
    const float* Wih0 = (const float*)d_in[1];
    const float* Whh0 = (const float*)d_in[2];
    const float* bih0 = (const float*)d_in[3];
    const float* bhh0 = (const float*)d_in[4];
    const float* Wih1 = (const float*)d_in[5];
    const float* Whh1 = (const float*)d_in[6];
    const float* bih1 = (const float*)d_in[7];
    const float* bhh1 = (const float*)d_in[8];
    const float* fc1w = (const float*)d_in[9];
    const float* fc1b = (const float*)d_in[10];
    const float* fc2w = (const float*)d_in[11];
    const float* fc2b = (const float*)d_in[12];
    float* out = (float*)d_out;

    int Tc = SEQT;
    while (Tc > SUBS) {
        size_t need = (size_t)BATCH * Tc * GATES * 4        // xp4
                    + ((size_t)GATES * INPUTD + 3 * (size_t)GATES * HID) * 2
                    + (size_t)128 * Tc * 512 * 2            // h0q
                    + 4 * (size_t)BATCH * HID * 4
                    + 128 * NCH * 4 + 512;
        if (need <= ws_size) break;
        Tc >>= 1;
    }
    int tcs = __builtin_ctz((unsigned)Tc);

    float*    xp   = (float*)d_ws;
    bf16_t*   wb0  = (bf16_t*)(xp + (size_t)BATCH * Tc * GATES);
    bf16_t*   wb1  = wb0 + (size_t)GATES * INPUTD;
    bf16_t*   wh0b = wb1 + (size_t)GATES * HID;
    bf16_t*   wh1b = wh0b + (size_t)GATES * HID;
    bf16_t*   h0q  = wh1b + (size_t)GATES * HID;
    float*    h0st = (float*)(h0q + (size_t)128 * Tc * 512);
    float*    c0st = h0st + (size_t)BATCH * HID;
    float*    h1st = c0st + (size_t)BATCH * HID;
    float*    c1st = h1st + (size_t)BATCH * HID;
    unsigned* flags = (unsigned*)(c1st + (size_t)BATCH * HID);

    // weights cvt + flags zeroing, one launch (flags re-zeroed every call)
    cvt_weights<<<449, 256, 0, stream>>>(Wih0, Wih1, Whh0, Whh1,
                                         wb0, wb1, wh0b, wh1b, flags);

    int nchunk = SEQT / Tc;
    dim3 gemm_grid(GATES / 128, (BATCH * Tc) / 128);

    for (int ci = 0; ci < nchunk; ++ci) {
        gemm_mfma<<<gemm_grid, 256, 0, stream>>>(
            x, wb0, bih0, bhh0, xp, INPUTD, tcs, Tc - 1, SEQT, ci * Tc);
        lstm_dual<<<256, 512, 0, stream>>>(
            xp, wh0b, wb1, wh1b, bih1, bhh1, h0q, flags,
            h0st, c0st, h1st, c1st, Tc, ci == 0, ci * (Tc / SUBS));
    }

    fc_head<<<BATCH, 128, 0, stream>>>(
        h0st, c0st, h1st, c1st, fc1w, fc1b, fc2w, fc2b, out);
}

// Round 17
// 575.812 us; speedup vs baseline: 1.3985x; 1.0189x over previous
//
#include <hip/hip_runtime.h>
#include <hip/hip_bf16.h>

// ---------------------------------------------------------------------------
// RecurrentBattleNet: 2-layer LSTM (B=512, T=256, IN=512, H=128) + FC head.
// Round 17: consumer DMA depth-2. R16's consumer waited vmcnt(0) on the
// image-(t+1) DMA within the SAME step it was issued (~300-900 cyc stall on
// the critical path every step; h0q is cross-XCD ~900 cyc). Now 4 rotating
// image slots: step t issues DMA(t+2); the vmcnt(0) for DMA(t+1) is done by
// its issuing wave ((t+3)&3) one full step after issue -> latency hidden.
// Producer / GEMM (fused f32->bf16 A) / head unchanged from R16.
// ---------------------------------------------------------------------------

#define BATCH 512
#define SEQT  256
#define INPUTD 512
#define HID   128
#define GATES 512   // 4*HID
#define RB    4     // batch rows per recurrence block
#define SUBS  16    // producer->consumer flag granularity (steps)
#define NCH   (SEQT / SUBS)

typedef __bf16 bf16_t;
typedef bf16_t bf16x4 __attribute__((ext_vector_type(4)));
typedef bf16_t bf16x8 __attribute__((ext_vector_type(8)));
typedef float  f32x4  __attribute__((ext_vector_type(4)));

__device__ __forceinline__ float sigm(float x) {
    return __builtin_amdgcn_rcpf(1.f + __expf(-x));
}
__device__ __forceinline__ float tanhfast(float x) {
    float xc = fminf(fmaxf(x, -15.f), 15.f);
    float e = __expf(2.f * xc);
    return (e - 1.f) * __builtin_amdgcn_rcpf(e + 1.f);
}

// ---------------------------------------------------------------------------
// Weights f32->bf16 (4 matrices) in one launch; block 448 zeroes the flags.
// ---------------------------------------------------------------------------
__global__ __launch_bounds__(256) void cvt_weights(
    const float* __restrict__ w0, const float* __restrict__ w1,
    const float* __restrict__ w2, const float* __restrict__ w3,
    bf16_t* __restrict__ o0, bf16_t* __restrict__ o1,
    bf16_t* __restrict__ o2, bf16_t* __restrict__ o3,
    unsigned* __restrict__ flags)
{
    int b = blockIdx.x;
    if (b == 448) {
        uint4 z = make_uint4(0u, 0u, 0u, 0u);
        #pragma unroll
        for (int i = 0; i < 4; ++i)
            ((uint4*)flags)[i * 256 + threadIdx.x] = z;
        return;
    }
    const float* src; bf16_t* dst; long base;
    if (b < 256)      { src = w0; dst = o0; base = (long)b * 256; }
    else if (b < 320) { src = w1; dst = o1; base = (long)(b - 256) * 256; }
    else if (b < 384) { src = w2; dst = o2; base = (long)(b - 320) * 256; }
    else              { src = w3; dst = o3; base = (long)(b - 384) * 256; }
    long i = base + threadIdx.x;
    float4 v = ((const float4*)src)[i];
    bf16x4 r;
    r[0] = (bf16_t)v.x; r[1] = (bf16_t)v.y;
    r[2] = (bf16_t)v.z; r[3] = (bf16_t)v.w;
    ((bf16x4*)dst)[i] = r;
}

// ---------------------------------------------------------------------------
// bf16 MFMA GEMM (layer-0 input projection), A read as f32 with in-register
// cvt (fused x conversion). Writes gate-major xp:
//   xp4[b>>2][t][gate][(b&3)*128 + hid]   (float)
// ---------------------------------------------------------------------------
__global__ __launch_bounds__(256) void gemm_mfma(
    const float* __restrict__ A, const bf16_t* __restrict__ W,
    const float* __restrict__ b1, const float* __restrict__ b2,
    float* __restrict__ out,
    int K, int tcs, int tcmask, int srcT, int t0)
{
    __shared__ bf16_t As[128 * 32];
    __shared__ bf16_t Bs[128 * 32];
    int tid = threadIdx.x;
    int l = tid & 63;
    int w = tid >> 6;
    int wm = w >> 1, wn = w & 1;
    int bn = blockIdx.x;
    int bm = blockIdx.y;
    int Tc = tcmask + 1;

    long aoff[2], boff[2];
    #pragma unroll
    for (int c = 0; c < 2; ++c) {
        int m = bm * 128 + (tid >> 2) + 64 * c;
        int xr = ((m >> tcs) * srcT) + t0 + (m & tcmask);
        aoff[c] = (long)xr * K + (tid & 3) * 8;
        int n = bn * 128 + (tid >> 2) + 64 * c;
        boff[c] = (long)n * K + (tid & 3) * 8;
    }

    f32x4 acc[4][4];
    #pragma unroll
    for (int i = 0; i < 4; ++i)
        #pragma unroll
        for (int j = 0; j < 4; ++j)
            acc[i][j] = (f32x4){0.f, 0.f, 0.f, 0.f};

    const int rbase = wm * 64 + (l & 15);
    const int cbase = wn * 64 + (l & 15);
    const int kfrag = (l >> 4) * 8;

    for (int kt = 0; kt < K; kt += 32) {
        float4 av[2][2];
        #pragma unroll
        for (int c = 0; c < 2; ++c) {
            av[c][0] = *(const float4*)(A + aoff[c] + kt);
            av[c][1] = *(const float4*)(A + aoff[c] + kt + 4);
        }
        __builtin_amdgcn_global_load_lds(
            (const __attribute__((address_space(1))) void*)(W + boff[0] + kt),
            (__attribute__((address_space(3))) void*)(Bs + tid * 8), 16, 0, 0);
        __builtin_amdgcn_global_load_lds(
            (const __attribute__((address_space(1))) void*)(W + boff[1] + kt),
            (__attribute__((address_space(3))) void*)(Bs + 2048 + tid * 8), 16, 0, 0);
        #pragma unroll
        for (int c = 0; c < 2; ++c) {
            bf16x8 ab;
            ab[0] = (bf16_t)av[c][0].x; ab[1] = (bf16_t)av[c][0].y;
            ab[2] = (bf16_t)av[c][0].z; ab[3] = (bf16_t)av[c][0].w;
            ab[4] = (bf16_t)av[c][1].x; ab[5] = (bf16_t)av[c][1].y;
            ab[6] = (bf16_t)av[c][1].z; ab[7] = (bf16_t)av[c][1].w;
            *(bf16x8*)(As + c * 2048 + tid * 8) = ab;
        }
        __syncthreads();

        bf16x8 af[4], bfr[4];
        #pragma unroll
        for (int i = 0; i < 4; ++i)
            af[i] = *(const bf16x8*)(As + (rbase + i * 16) * 32 + kfrag);
        #pragma unroll
        for (int j = 0; j < 4; ++j)
            bfr[j] = *(const bf16x8*)(Bs + (cbase + j * 16) * 32 + kfrag);

        #pragma unroll
        for (int i = 0; i < 4; ++i)
            #pragma unroll
            for (int j = 0; j < 4; ++j)
                acc[i][j] = __builtin_amdgcn_mfma_f32_16x16x32_bf16(
                    af[i], bfr[j], acc[i][j], 0, 0, 0);
        __syncthreads();
    }

    #pragma unroll
    for (int i = 0; i < 4; ++i) {
        int m0 = bm * 128 + wm * 64 + i * 16 + (l >> 4) * 4;
        #pragma unroll
        for (int j = 0; j < 4; ++j) {
            int n = bn * 128 + wn * 64 + j * 16 + (l & 15);
            float bb = b1[n] + b2[n];
            int hid = n & 127;          // g == bn
            #pragma unroll
            for (int r = 0; r < 4; ++r) {
                int m = m0 + r;
                int b = m >> tcs;
                int t = m & tcmask;
                int br = b >> 2, brow = b & 3;
                out[(((long)br * Tc + t) * 4 + bn) * 512 + brow * 128 + hid] =
                    acc[i][j][r] + bb;
            }
        }
    }
}

// ---------------------------------------------------------------------------
// Dual-role recurrence kernel. 256 blocks x 512 threads.
//   blocks 0-127  : layer-0 recurrence (producer)
//   blocks 128-255: layer-1 recurrence (consumer, depth-2 DMA pipeline)
// ---------------------------------------------------------------------------
#define BARRIER_()                                                             \
    do {                                                                       \
        asm volatile("s_waitcnt lgkmcnt(0)" ::: "memory");                     \
        __builtin_amdgcn_s_barrier();                                          \
        __builtin_amdgcn_sched_barrier(0);                                     \
    } while (0)

#define REC0_STEP(X, t)                                                        \
    {                                                                          \
        bf16x8 a[4];                                                           \
        _Pragma("unroll")                                                      \
        for (int ks = 0; ks < 4; ++ks) {                                       \
            int ba = (col * 256 + ks * 64 + lgroup * 16) ^ ((col & 7) << 4);   \
            a[ks] = *(const bf16x8*)((const char*)h_lds + ba);                 \
        }                                                                      \
        f32x4 acc[4];                                                          \
        _Pragma("unroll")                                                      \
        for (int g = 0; g < 4; ++g) acc[g] = (f32x4){0.f, 0.f, 0.f, 0.f};      \
        _Pragma("unroll")                                                      \
        for (int ks = 0; ks < 4; ++ks)                                         \
            _Pragma("unroll")                                                  \
            for (int g = 0; g < 4; ++g)                                        \
                acc[g] = __builtin_amdgcn_mfma_f32_16x16x32_bf16(              \
                    a[ks], __builtin_bit_cast(bf16x8, wreg[g][ks]), acc[g],    \
                    0, 0, 0);                                                  \
        if (lgroup == 0) {                                                     \
            _Pragma("unroll")                                                  \
            for (int r = 0; r < 4; ++r) {                                      \
                f32x4 v;                                                       \
                v[0] = acc[0][r]; v[1] = acc[1][r];                            \
                v[2] = acc[2][r]; v[3] = acc[3][r];                            \
                *(f32x4*)((char*)g_lds + r * 2048 + coff * 16) = v;            \
            }                                                                  \
        }                                                                      \
        BARRIER_();                                                            \
        {                                                                      \
            f32x4 gv = *(const f32x4*)((const char*)g_lds + tid * 16);         \
            float zi = gv[0] + X.x, zf = gv[1] + X.y;                          \
            float zg = gv[2] + X.z, zo = gv[3] + X.w;                          \
            c = sigm(zf) * c + sigm(zi) * tanhfast(zg);                        \
            h = sigm(zo) * tanhfast(c);                                        \
            *(bf16_t*)((char*)h_lds + hba) = (bf16_t)h;                        \
            h0qp[(long)(t) * 512] = (bf16_t)h;                                 \
        }                                                                      \
        if ((t) + 2 < Tc) {                                                    \
            long o = (long)((t) + 2) * 2048;                                   \
            X.x = xpt[o];        X.y = xpt[o + 512];                           \
            X.z = xpt[o + 1024]; X.w = xpt[o + 1536];                          \
        }                                                                      \
        if (((t) & (SUBS - 1)) == SUBS - 1)                                    \
            asm volatile("s_waitcnt vmcnt(0)" ::: "memory");                   \
        BARRIER_();                                                            \
        if ((((t) & (SUBS - 1)) == SUBS - 1) && tid == 0) {                    \
            __threadfence();                                                   \
            __hip_atomic_store(flagp + ((t) >> 4), 1u, __ATOMIC_RELEASE,       \
                               __HIP_MEMORY_SCOPE_AGENT);                      \
        }                                                                      \
    }

__global__ __launch_bounds__(512, 2) void lstm_dual(
    const float* __restrict__ xp4,   // [B/4][Tc][4][512] layer-0 projection
    const bf16_t* __restrict__ Wh0,  // Whh0 bf16 [512][128]
    const bf16_t* __restrict__ Wi1,  // Wih1 bf16 [512][128]
    const bf16_t* __restrict__ Wh1,  // Whh1 bf16 [512][128]
    const float* __restrict__ bih1, const float* __restrict__ bhh1,
    bf16_t* __restrict__ h0q,        // [128][Tc][512] swizzled h0 images
    unsigned* __restrict__ flags,    // [128][NCH]
    float* __restrict__ h0st, float* __restrict__ c0st,
    float* __restrict__ h1st, float* __restrict__ c1st,
    int Tc, int first, int subbase)
{
    __shared__ __align__(16) char pool[36 * 1024];
    int tid = threadIdx.x;
    int l = tid & 63;
    int wv = tid >> 6;                // wave 0..7
    int pair = blockIdx.x & 127;
    int r0 = pair * RB;
    int col = l & 15;
    int lgroup = l >> 4;              // 0..3
    int kreg = lgroup * 8;
    int erow = tid >> 7, ehid = tid & 127;
    const int hba = (erow * 256 + ehid * 2) ^ ((erow & 7) << 4);
    unsigned* flagp = flags + pair * NCH + subbase;

    if (blockIdx.x < 128) {
        // ================= producer: layer-0 recurrence =================
        bf16_t* h_lds = (bf16_t*)pool;           // 4 KB (16 rows, swizzled)
        float*  g_lds = (float*)(pool + 4096);   // 8 KB
        int coff = wv * 16 + col;                // owned gate-col

        f32x4 wreg[4][4];
        #pragma unroll
        for (int g = 0; g < 4; ++g)
            #pragma unroll
            for (int ks = 0; ks < 4; ++ks)
                wreg[g][ks] = *(const f32x4*)(Wh0 + (long)(g * 128 + coff) * HID
                                              + ks * 32 + kreg);
        #pragma unroll
        for (int g = 0; g < 4; ++g)
            #pragma unroll
            for (int ks = 0; ks < 4; ++ks)
                asm volatile("" : "+a"(wreg[g][ks]));

        float c = first ? 0.f : c0st[(r0 + erow) * HID + ehid];
        float h = first ? 0.f : h0st[(r0 + erow) * HID + ehid];

        ((float2*)h_lds)[tid & 255] = make_float2(0.f, 0.f);   // zero 4 KB
        __syncthreads();
        *(bf16_t*)((char*)h_lds + hba) = (bf16_t)h;
        __syncthreads();

        const float* xpt = xp4 + (long)pair * Tc * 2048 + tid;
        bf16_t* h0qp = h0q + (long)pair * Tc * 512 + (hba >> 1);
        float4 xA, xB;
        xA.x = xpt[0];    xA.y = xpt[512];
        xA.z = xpt[1024]; xA.w = xpt[1536];
        if (Tc > 1) {
            xB.x = xpt[2048];        xB.y = xpt[2048 + 512];
            xB.z = xpt[2048 + 1024]; xB.w = xpt[2048 + 1536];
        } else {
            xB = make_float4(0.f, 0.f, 0.f, 0.f);
        }

        for (int tt = 0; tt < Tc; tt += 2) {
            REC0_STEP(xA, tt)
            REC0_STEP(xB, tt + 1)
        }

        h0st[(r0 + erow) * HID + ehid] = h;
        c0st[(r0 + erow) * HID + ehid] = c;
    } else {
        // ===== consumer: layer-1 recurrence, depth-2 DMA pipeline =======
        bf16_t* h0stg = (bf16_t*)pool;             // 4 slots x 4 KB
        bf16_t* h1_lds = (bf16_t*)(pool + 16384);  // 4 KB
        float*  g1a = (float*)(pool + 20480);      // 8 KB (Wi1@h0 partial)
        float*  g1b = (float*)(pool + 28672);      // 8 KB (Wh1@h1 partial)
        int isWi = wv < 4;
        int w4 = wv & 3;                           // wave-within-role
        int coff1 = w4 * 32;                       // owned 32-col base

        const bf16_t* Wsrc = isWi ? Wi1 : Wh1;
        f32x4 wreg[2][4][4];
        #pragma unroll
        for (int c2 = 0; c2 < 2; ++c2)
            #pragma unroll
            for (int g = 0; g < 4; ++g)
                #pragma unroll
                for (int ks = 0; ks < 4; ++ks)
                    wreg[c2][g][ks] = *(const f32x4*)(
                        Wsrc + (long)(g * 128 + coff1 + c2 * 16 + col) * HID
                        + ks * 32 + kreg);
        #pragma unroll
        for (int c2 = 0; c2 < 2; ++c2)
            #pragma unroll
            for (int g = 0; g < 4; ++g)
                #pragma unroll
                for (int ks = 0; ks < 4; ++ks)
                    asm volatile("" : "+a"(wreg[c2][g][ks]));

        float4 bias1;
        bias1.x = bih1[ehid]       + bhh1[ehid];
        bias1.y = bih1[128 + ehid] + bhh1[128 + ehid];
        bias1.z = bih1[256 + ehid] + bhh1[256 + ehid];
        bias1.w = bih1[384 + ehid] + bhh1[384 + ehid];

        float c1 = first ? 0.f : c1st[(r0 + erow) * HID + ehid];
        float h1 = first ? 0.f : h1st[(r0 + erow) * HID + ehid];

        // zero h0stg (16 KB) + h1_lds (4 KB) = 20 KB
        #pragma unroll
        for (int i = 0; i < 5; ++i)
            ((float2*)pool)[i * 512 + tid] = make_float2(0.f, 0.f);
        __syncthreads();
        *(bf16_t*)((char*)h1_lds + hba) = (bf16_t)h1;
        __syncthreads();

        // prologue: wait chunk 0; stage images 0 and 1 into slots 0,1
        if (wv == 0) {
            while (__hip_atomic_load(flagp, __ATOMIC_ACQUIRE,
                                     __HIP_MEMORY_SCOPE_AGENT) == 0u)
                __builtin_amdgcn_s_sleep(2);
            __builtin_amdgcn_global_load_lds(
                (const __attribute__((address_space(1))) void*)(
                    h0q + (long)pair * Tc * 512 + l * 8),
                (__attribute__((address_space(3))) void*)h0stg, 16, 0, 0);
            if (Tc > 1)
                __builtin_amdgcn_global_load_lds(
                    (const __attribute__((address_space(1))) void*)(
                        h0q + ((long)pair * Tc + 1) * 512 + l * 8),
                    (__attribute__((address_space(3))) void*)(h0stg + 2048),
                    16, 0, 0);
            asm volatile("s_waitcnt vmcnt(0)" ::: "memory");
        }
        __syncthreads();

        for (int t = 0; t < Tc; ++t) {
            // issue DMA for image t+2 into slot (t+2)&3 (wave t&3)
            if (t + 2 < Tc && wv == (t & 3)) {
                if (((t + 2) & (SUBS - 1)) == 0) {
                    unsigned* fp = flagp + ((t + 2) >> 4);
                    while (__hip_atomic_load(fp, __ATOMIC_ACQUIRE,
                                             __HIP_MEMORY_SCOPE_AGENT) == 0u)
                        __builtin_amdgcn_s_sleep(2);
                }
                __builtin_amdgcn_global_load_lds(
                    (const __attribute__((address_space(1))) void*)(
                        h0q + ((long)pair * Tc + t + 2) * 512 + l * 8),
                    (__attribute__((address_space(3))) void*)(
                        h0stg + ((t + 2) & 3) * 2048), 16, 0, 0);
            }

            // phase A: partial gates (slot t&3)
            const char* asrc = isWi
                ? (const char*)(h0stg + (t & 3) * 2048)
                : (const char*)h1_lds;
            bf16x8 a[4];
            #pragma unroll
            for (int ks = 0; ks < 4; ++ks) {
                int ba = (col * 256 + ks * 64 + lgroup * 16) ^ ((col & 7) << 4);
                a[ks] = *(const bf16x8*)(asrc + ba);
            }
            float* gdst = isWi ? g1a : g1b;
            #pragma unroll
            for (int c2 = 0; c2 < 2; ++c2) {
                f32x4 acc[4];
                #pragma unroll
                for (int g = 0; g < 4; ++g) acc[g] = (f32x4){0.f, 0.f, 0.f, 0.f};
                #pragma unroll
                for (int ks = 0; ks < 4; ++ks)
                    #pragma unroll
                    for (int g = 0; g < 4; ++g)
                        acc[g] = __builtin_amdgcn_mfma_f32_16x16x32_bf16(
                            a[ks], __builtin_bit_cast(bf16x8, wreg[c2][g][ks]),
                            acc[g], 0, 0, 0);
                if (lgroup == 0) {
                    #pragma unroll
                    for (int r = 0; r < 4; ++r) {
                        f32x4 v;
                        v[0] = acc[0][r]; v[1] = acc[1][r];
                        v[2] = acc[2][r]; v[3] = acc[3][r];
                        *(f32x4*)((char*)gdst + r * 2048 +
                                  (coff1 + c2 * 16 + col) * 16) = v;
                    }
                }
            }
            BARRIER_();

            // phase B: ew (sum partials + bias)
            {
                f32x4 gva = *(const f32x4*)((const char*)g1a + tid * 16);
                f32x4 gvb = *(const f32x4*)((const char*)g1b + tid * 16);
                float zi = gva[0] + gvb[0] + bias1.x;
                float zf = gva[1] + gvb[1] + bias1.y;
                float zg = gva[2] + gvb[2] + bias1.z;
                float zo = gva[3] + gvb[3] + bias1.w;
                c1 = sigm(zf) * c1 + sigm(zi) * tanhfast(zg);
                h1 = sigm(zo) * tanhfast(c1);
                *(bf16_t*)((char*)h1_lds + hba) = (bf16_t)h1;
            }
            // wave ((t+3)&3) issued DMA(t+1) at step t-1: wait now (1 full
            // step in flight -> latency hidden), before next step reads it.
            if (t + 1 < Tc && wv == ((t + 3) & 3))
                asm volatile("s_waitcnt vmcnt(0)" ::: "memory");
            BARRIER_();
        }

        h1st[(r0 + erow) * HID + ehid] = h1;
        c1st[(r0 + erow) * HID + ehid] = c1;
    }
}

// ---------------------------------------------------------------------------
// FC head + softmax + state copy-out. One block per batch row, 128 threads.
// out layout: probs [512*10] | h_n [2*512*128] | c_n [2*512*128]
// ---------------------------------------------------------------------------
__global__ __launch_bounds__(128) void fc_head(
    const float* __restrict__ h0st, const float* __restrict__ c0st,
    const float* __restrict__ h1st, const float* __restrict__ c1st,
    const float* __restrict__ fc1w, const float* __restrict__ fc1b,
    const float* __restrict__ fc2w, const float* __restrict__ fc2b,
    float* __restrict__ out)
{
    __shared__ float h1_s[HID];
    __shared__ float hid_s[64];
    __shared__ float log_s[10];
    int t = threadIdx.x;
    int b = blockIdx.x;

    h1_s[t] = h1st[b * HID + t];
    __syncthreads();

    if (t < 64) {
        float a = fc1b[t];
        const float* wrow = fc1w + t * HID;
        #pragma unroll 4
        for (int k = 0; k < HID; ++k) a = fmaf(wrow[k], h1_s[k], a);
        hid_s[t] = fmaxf(a, 0.f);
    }
    __syncthreads();

    if (t < 10) {
        float a = fc2b[t];
        const float* wrow = fc2w + t * 64;
        #pragma unroll 4
        for (int k = 0; k < 64; ++k) a = fmaf(wrow[k], hid_s[k], a);
        log_s[t] = a;
    }
    __syncthreads();

    if (t == 0) {
        float m = log_s[0];
        #pragma unroll
        for (int j = 1; j < 10; ++j) m = fmaxf(m, log_s[j]);
        float e[10];
        float s = 0.f;
        #pragma unroll
        for (int j = 0; j < 10; ++j) { e[j] = __expf(log_s[j] - m); s += e[j]; }
        float inv = __builtin_amdgcn_rcpf(s);
        #pragma unroll
        for (int j = 0; j < 10; ++j) out[b * 10 + j] = e[j] * inv;
    }

    float* hn = out + BATCH * 10;
    float* cn = hn + 2 * BATCH * HID;
    hn[b * HID + t] = h0st[b * HID + t];
    hn[BATCH * HID + b * HID + t] = h1_s[t];
    cn[b * HID + t] = c0st[b * HID + t];
    cn[BATCH * HID + b * HID + t] = c1st[b * HID + t];
}

// ---------------------------------------------------------------------------
extern "C" void kernel_launch(void* const* d_in, const int* in_sizes, int n_in,
                              void* d_out, int out_size, void* d_ws, size_t ws_size,
                              hipStream_t stream) {
    const float* x    = (const float*)d_in[0];
    const float* Wih0 = (const float*)d_in[1];
    const float* Whh0 = (const float*)d_in[2];
    const float* bih0 = (const float*)d_in[3];
    const float* bhh0 = (const float*)d_in[4];
    const float* Wih1 = (const float*)d_in[5];
    const float* Whh1 = (const float*)d_in[6];
    const float* bih1 = (const float*)d_in[7];
    const float* bhh1 = (const float*)d_in[8];
    const float* fc1w = (const float*)d_in[9];
    const float* fc1b = (const float*)d_in[10];
    const float* fc2w = (const float*)d_in[11];
    const float* fc2b = (const float*)d_in[12];
    float* out = (float*)d_out;

    int Tc = SEQT;
    while (Tc > SUBS) {
        size_t need = (size_t)BATCH * Tc * GATES * 4        // xp4
                    + ((size_t)GATES * INPUTD + 3 * (size_t)GATES * HID) * 2
                    + (size_t)128 * Tc * 512 * 2            // h0q
                    + 4 * (size_t)BATCH * HID * 4
                    + 128 * NCH * 4 + 512;
        if (need <= ws_size) break;
        Tc >>= 1;
    }
    int tcs = __builtin_ctz((unsigned)Tc);

    float*    xp   = (float*)d_ws;
    bf16_t*   wb0  = (bf16_t*)(xp + (size_t)BATCH * Tc * GATES);
    bf16_t*   wb1  = wb0 + (size_t)GATES * INPUTD;
    bf16_t*   wh0b = wb1 + (size_t)GATES * HID;
    bf16_t*   wh1b = wh0b + (size_t)GATES * HID;
    bf16_t*   h0q  = wh1b + (size_t)GATES * HID;
    float*    h0st = (float*)(h0q + (size_t)128 * Tc * 512);
    float*    c0st = h0st + (size_t)BATCH * HID;
    float*    h1st = c0st + (size_t)BATCH * HID;
    float*    c1st = h1st + (size_t)BATCH * HID;
    unsigned* flags = (unsigned*)(c1st + (size_t)BATCH * HID);

    cvt_weights<<<449, 256, 0, stream>>>(Wih0, Wih1, Whh0, Whh1,
                                         wb0, wb1, wh0b, wh1b, flags);

    int nchunk = SEQT / Tc;
    dim3 gemm_grid(GATES / 128, (BATCH * Tc) / 128);

    for (int ci = 0; ci < nchunk; ++ci) {
        gemm_mfma<<<gemm_grid, 256, 0, stream>>>(
            x, wb0, bih0, bhh0, xp, INPUTD, tcs, Tc - 1, SEQT, ci * Tc);
        lstm_dual<<<256, 512, 0, stream>>>(
            xp, wh0b, wb1, wh1b, bih1, bhh1, h0q, flags,
            h0st, c0st, h1st, c1st, Tc, ci == 0, ci * (Tc / SUBS));
    }

    fc_head<<<BATCH, 128, 0, stream>>>(
        h0st, c0st, h1st, c1st, fc1w, fc1b, fc2w, fc2b, out);
}